// Round 3
// baseline (4507.179 us; speedup 1.0000x reference)
//
#include <hip/hip_runtime.h>
#include <cstdint>

// LSTM fused kernel for MI355X — round 3.
// 64 blocks (1/batch) x 512 threads (2 gate-rows/thread), full T-loop in-kernel.
// Key changes vs r2: launch_bounds(512,2) so int8 weights live in VGPRs (r2's
// (1024,4) forced AGPRs -> accvgpr_read per dot4, ~2x VALU); gate exchange via
// intra-wave shfl_xor(32) (i,g in lanes 0-31; f,o in lanes 32-63) -> ONE
// barrier/step, no LDS; x-path hoisted to a prep GEMM (xg f16) when ws fits;
// fc hoisted to a post-pass kernel over stored f16 h.

#define B_  64
#define T_  2048
#define I_  32
#define H_  256
#define G4  1024
#define O_  32

typedef int v16i __attribute__((ext_vector_type(16)));
typedef int v8i  __attribute__((ext_vector_type(8)));
typedef _Float16 h2_t __attribute__((ext_vector_type(2)));

#if __has_builtin(__builtin_amdgcn_sdot4)
__device__ __forceinline__ int dot4(int a, int b, int c) {
    return __builtin_amdgcn_sdot4(a, b, c, false);
}
#else
__device__ __forceinline__ int dot4(int a, int b, int c) {
    c += (int)(int8_t)(a)        * (int)(int8_t)(b);
    c += (int)(int8_t)(a >> 8)   * (int)(int8_t)(b >> 8);
    c += (int)(int8_t)(a >> 16)  * (int)(int8_t)(b >> 16);
    c += (int)(int8_t)(a >> 24)  * (int)(int8_t)(b >> 24);
    return c;
}
#endif

__device__ __forceinline__ float fdot2h(h2_t a, h2_t b, float c) {
#if __has_builtin(__builtin_amdgcn_fdot2)
    return __builtin_amdgcn_fdot2(a, b, c, false);
#else
    return c + (float)a[0] * (float)b[0] + (float)a[1] * (float)b[1];
#endif
}

// ---------------- ws layout ----------------
#define QWHH_OFF 0u                         // uint32 [128][512] = 262144 B
#define QWIH_OFF 262144u                    // uint32 [32][512]  = 65536 B (fallback)
#define S1_OFF   327680u                    // float [1024]
#define S2_OFF   331776u                    // float [1024]
#define BIAS_OFF 335872u                    // float [1024]
#define HBUF_OFF 339968u                    // 64 * 2049 * 320 = 41,963,520
#define HREC_STRIDE 320
#define HSLOTS 2049
#define HSTORE_OFF (339968u + 41963520u)            // 42,303,488 ; f16 [131072][256] = 67,108,864
#define XQ_OFF  (HSTORE_OFF + 67108864u)            // fallback: uint32 [131072][16] = 8,388,608
#define XS_OFF  (XQ_OFF + 8388608u)                 // fallback: float [131072]
#define XG_OFF  (HSTORE_OFF + 67108864u)            // full: uint32 [131072][512] = 268,435,456
#define FULL_NEED  ((size_t)XG_OFF + 268435456ull)
#define FB_NEED    ((size_t)XS_OFF + 524288ull)

__device__ __forceinline__ uint32_t pack_q(int q0, int q1, int q2, int q3) {
    return  ((uint32_t)(uint8_t)(int8_t)q0)
          | (((uint32_t)(uint8_t)(int8_t)q1) << 8)
          | (((uint32_t)(uint8_t)(int8_t)q2) << 16)
          | (((uint32_t)(uint8_t)(int8_t)q3) << 24);
}
__device__ __forceinline__ int clamp127(int v) {
    return v < -127 ? -127 : (v > 127 ? 127 : v);
}

// thread-column mapping shared by prep_w / gemm_xg / lstm_main:
// tid in [0,512): w_=tid>>6, l=tid&63, j=32*w_+(l&31), up=(l>=32)
// rowA = up ? 256+j : j        (f or i)
// rowB = up ? 768+j : 512+j    (o or g)

// -------- prep: quantize W_hh (+W_ih for fallback), permuted columns --------
__global__ __launch_bounds__(64) void prep_w(
    const float* __restrict__ Whh, const float* __restrict__ Wih,
    const float* __restrict__ bih, const float* __restrict__ bhh,
    uint32_t* __restrict__ qwhh, uint32_t* __restrict__ qwih,
    float* __restrict__ s1, float* __restrict__ s2, float* __restrict__ bias)
{
    const int r = blockIdx.x;           // gate row 0..1023
    const int l = threadIdx.x;          // 0..63
    const int j = r & 255, g = r >> 8;
    const int col = 64 * (j >> 5) + ((g & 1) ? 32 : 0) + (j & 31);
    const int dbase = (g >= 2) ? 64 : 0;        // rowB slot
    const int xbase = (g >= 2) ? 16 : 0;

    const float4 wv = ((const float4*)(Whh + r * H_))[l];
    float m = fmaxf(fmaxf(fabsf(wv.x), fabsf(wv.y)), fmaxf(fabsf(wv.z), fabsf(wv.w)));
    #pragma unroll
    for (int s = 1; s < 64; s <<= 1) m = fmaxf(m, __shfl_xor(m, s, 64));
    const float S1 = fmaxf(m, 1e-20f) / 127.f;

    float xm = (l < I_) ? fabsf(Wih[r * I_ + l]) : 0.f;
    #pragma unroll
    for (int s = 1; s < 64; s <<= 1) xm = fmaxf(xm, __shfl_xor(xm, s, 64));
    const float S2 = fmaxf(xm, 1e-20f) / 127.f;

    {
        const float r1 = 1.f / S1;
        qwhh[(dbase + l) * 512 + col] = pack_q(
            clamp127((int)rintf(wv.x * r1)), clamp127((int)rintf(wv.y * r1)),
            clamp127((int)rintf(wv.z * r1)), clamp127((int)rintf(wv.w * r1)));
    }
    if (l < 8) {   // W_ih hi
        const float4 xw = ((const float4*)(Wih + r * I_))[l];
        const float r2 = 1.f / S2;
        qwih[(xbase + l) * 512 + col] = pack_q(
            clamp127((int)rintf(xw.x * r2)), clamp127((int)rintf(xw.y * r2)),
            clamp127((int)rintf(xw.z * r2)), clamp127((int)rintf(xw.w * r2)));
    } else if (l < 16) {  // W_ih lo
        const int jj = l - 8;
        const float4 xw = ((const float4*)(Wih + r * I_))[jj];
        const float r2 = 1.f / S2;
        float v0 = xw.x * r2, v1 = xw.y * r2, v2 = xw.z * r2, v3 = xw.w * r2;
        int a0 = clamp127((int)rintf(v0)), a1 = clamp127((int)rintf(v1));
        int a2 = clamp127((int)rintf(v2)), a3 = clamp127((int)rintf(v3));
        qwih[(xbase + 8 + jj) * 512 + col] = pack_q(
            clamp127((int)rintf((v0 - (float)a0) * 127.f)),
            clamp127((int)rintf((v1 - (float)a1) * 127.f)),
            clamp127((int)rintf((v2 - (float)a2) * 127.f)),
            clamp127((int)rintf((v3 - (float)a3) * 127.f)));
    }
    if (l == 0) { s1[r] = S1; s2[r] = S2; bias[r] = bih[r] + bhh[r]; }
}

// -------- prep (full): xg[bt][tid] = f16 pair (W_ih.x + b) for rowA/rowB ----
__global__ __launch_bounds__(512, 4) void gemm_xg(
    const float* __restrict__ x, const float* __restrict__ Wih,
    const float* __restrict__ biasv, uint32_t* __restrict__ xg)
{
    const int b  = blockIdx.x >> 3;
    const int t0 = (blockIdx.x & 7) * 256;
    const int tid = threadIdx.x;
    const int w_ = tid >> 6, l = tid & 63;
    const int j = 32 * w_ + (l & 31);
    const bool up = (l >= 32);
    const int rowA = up ? 256 + j : j;
    const int rowB = up ? 768 + j : 512 + j;

    float wa[32], wb[32];
    #pragma unroll
    for (int k4 = 0; k4 < 8; k4++) {
        const float4 va = ((const float4*)(Wih + rowA * I_))[k4];
        const float4 vb = ((const float4*)(Wih + rowB * I_))[k4];
        wa[4*k4] = va.x; wa[4*k4+1] = va.y; wa[4*k4+2] = va.z; wa[4*k4+3] = va.w;
        wb[4*k4] = vb.x; wb[4*k4+1] = vb.y; wb[4*k4+2] = vb.z; wb[4*k4+3] = vb.w;
    }
    const float biasA = biasv[rowA], biasB = biasv[rowB];

    for (int tt = 0; tt < 256; tt++) {
        const float* xrow = x + ((size_t)b * T_ + t0 + tt) * I_;
        v16i x0, x1;
        asm volatile("s_load_dwordx16 %0, %2, 0x0\n\t"
                     "s_load_dwordx16 %1, %2, 0x40\n\t"
                     "s_waitcnt lgkmcnt(0)"
                     : "=&s"(x0), "=&s"(x1) : "s"(xrow) : "memory");
        float a = biasA, bsum = biasB;
        #pragma unroll
        for (int k = 0; k < 16; k++) {
            a    = fmaf(wa[k], __int_as_float(x0[k]), a);
            bsum = fmaf(wb[k], __int_as_float(x0[k]), bsum);
        }
        #pragma unroll
        for (int k = 0; k < 16; k++) {
            a    = fmaf(wa[16+k], __int_as_float(x1[k]), a);
            bsum = fmaf(wb[16+k], __int_as_float(x1[k]), bsum);
        }
        union { h2_t h; uint32_t u; } cv;
        cv.h[0] = (_Float16)a; cv.h[1] = (_Float16)bsum;
        xg[((size_t)b * T_ + t0 + tt) * 512 + tid] = cv.u;
    }
}

// -------- prep (fallback): quantize x --------
__global__ __launch_bounds__(256) void prep_x(
    const float* __restrict__ x, uint32_t* __restrict__ xq, float* __restrict__ xs)
{
    __shared__ float xb[64 * 32];
    const int base = blockIdx.x * 64 * 32;
    for (int i = threadIdx.x; i < 2048; i += 256) xb[i] = x[base + i];
    __syncthreads();
    const int t = threadIdx.x;
    if (t < 64) {
        float m = 0.f;
        for (int k = 0; k < 32; k++) m = fmaxf(m, fabsf(xb[t * 32 + k]));
        const float S = fmaxf(m, 1e-20f) / 127.f;
        const int row = blockIdx.x * 64 + t;
        xs[row] = S;
        const float rS = 1.f / S;
        for (int jj = 0; jj < 8; jj++) {
            int qa[4], qb[4];
            for (int e = 0; e < 4; e++) {
                float v = xb[t * 32 + jj * 4 + e] * rS;
                int a = clamp127((int)rintf(v));
                int b = clamp127((int)rintf((v - (float)a) * 127.f));
                qa[e] = a; qb[e] = b;
            }
            xq[row * 16 + jj]     = pack_q(qa[0], qa[1], qa[2], qa[3]);
            xq[row * 16 + 8 + jj] = pack_q(qb[0], qb[1], qb[2], qb[3]);
        }
    }
}

#define GRP(GACC, WOFF, HV, HOFF, SC) { int acc_ = 0; \
    acc_ = dot4((int)w[(WOFF)+0], HV[(HOFF)+0], acc_); \
    acc_ = dot4((int)w[(WOFF)+1], HV[(HOFF)+1], acc_); \
    acc_ = dot4((int)w[(WOFF)+2], HV[(HOFF)+2], acc_); \
    acc_ = dot4((int)w[(WOFF)+3], HV[(HOFF)+3], acc_); \
    acc_ = dot4((int)w[(WOFF)+4], HV[(HOFF)+4], acc_); \
    acc_ = dot4((int)w[(WOFF)+5], HV[(HOFF)+5], acc_); \
    acc_ = dot4((int)w[(WOFF)+6], HV[(HOFF)+6], acc_); \
    acc_ = dot4((int)w[(WOFF)+7], HV[(HOFF)+7], acc_); \
    GACC = fmaf((float)acc_, (SC), GACC); }

// -------- main: full LSTM, one block per batch, 512 threads, 2 rows/thread --
template<bool USE_XG>
__global__ __launch_bounds__(512, 2) void lstm_main(
    const uint32_t* __restrict__ qwhh, const uint32_t* __restrict__ qwih,
    const float* __restrict__ s1v, const float* __restrict__ s2v,
    const float* __restrict__ biasv,
    const uint32_t* __restrict__ xg,
    const uint32_t* __restrict__ xq, const float* __restrict__ xs,
    char* __restrict__ hbuf, _Float16* __restrict__ hstore)
{
    const int b   = blockIdx.x;
    const int tid = threadIdx.x;
    const int w_  = tid >> 6, l = tid & 63;
    const int j   = 32 * w_ + (l & 31);
    const bool up = (l >= 32);
    const int rowA = up ? 256 + j : j;       // i (or f)
    const int rowB = up ? 768 + j : 512 + j; // g (or o)

    uint32_t w[128];
    #pragma unroll
    for (int d = 0; d < 128; d++) w[d] = qwhh[d * 512 + tid];
    const float S1A = s1v[rowA], S1B = s1v[rowB];

    uint32_t wxa[16], wxb[16];
    float S2A = 0.f, S2B = 0.f, biasA = 0.f, biasB = 0.f;
    if (!USE_XG) {
        #pragma unroll
        for (int k = 0; k < 16; k++) {
            wxa[k] = qwih[k * 512 + tid];
            wxb[k] = qwih[(16 + k) * 512 + tid];
        }
        S2A = s2v[rowA]; S2B = s2v[rowB];
        biasA = biasv[rowA]; biasB = biasv[rowB];
    }

    char* hb = hbuf + (size_t)b * ((size_t)HSLOTS * HREC_STRIDE);
    if (tid < 72) ((uint32_t*)(hb + 2048 * HREC_STRIDE))[tid] = 0u;  // zero h + zero scales

    const uint32_t* xgb = USE_XG ? (xg + (size_t)b * T_ * 512 + tid) : nullptr;
    const uint32_t* xqb = xq + (size_t)b * T_ * 16;
    const float*    xsb = xs + (size_t)b * T_;
    _Float16*       hsb = hstore + (size_t)b * T_ * H_;

    float c_state = 0.f;     // valid for lanes l<32
    uint32_t xg_cur = 0;
    if (USE_XG) xg_cur = xgb[0];
    __syncthreads();   // init stores drained

    for (int t = 0; t < T_; t++) {
        const uint32_t slot = (t == 0) ? 2048u : ((uint32_t)(t * 1993) & 2047u);
        const char* hrec = hb + (size_t)slot * HREC_STRIDE;
        v16i h0, h1, h2, h3; v8i scv;
        asm volatile("s_load_dwordx16 %0, %5, 0x0\n\t"
                     "s_load_dwordx16 %1, %5, 0x40\n\t"
                     "s_load_dwordx16 %2, %5, 0x80\n\t"
                     "s_load_dwordx16 %3, %5, 0xc0\n\t"
                     "s_load_dwordx8  %4, %5, 0x100\n\t"
                     "s_waitcnt lgkmcnt(0)"
                     : "=&s"(h0), "=&s"(h1), "=&s"(h2), "=&s"(h3), "=&s"(scv)
                     : "s"(hrec)
                     : "memory");

        // prefetch next xg (in flight across this iteration; drained at barrier)
        uint32_t xg_nxt = 0;
        if (USE_XG && t + 1 < T_) xg_nxt = xgb[(size_t)(t + 1) * 512];

        float xA, xB;
        if (USE_XG) {
            union { uint32_t u; h2_t h; } cv; cv.u = xg_cur;
            xA = (float)cv.h[0]; xB = (float)cv.h[1];
        } else {
            v16i xv; int sxi;
            const uint32_t* pxq = xqb + (size_t)t * 16;
            const float*    pxs = xsb + t;
            asm volatile("s_load_dwordx16 %0, %2, 0x0\n\t"
                         "s_load_dword %1, %3, 0x0\n\t"
                         "s_waitcnt lgkmcnt(0)"
                         : "=&s"(xv), "=&s"(sxi) : "s"(pxq), "s"(pxs) : "memory");
            int aA = 0, aM = 0, bA = 0, bM = 0;
            #pragma unroll
            for (int k = 0; k < 8; k++) {
                aA = dot4((int)wxa[k],     xv[k],     aA);
                aM = dot4((int)wxa[8 + k], xv[k],     aM);
                aM = dot4((int)wxa[k],     xv[8 + k], aM);
                bA = dot4((int)wxb[k],     xv[k],     bA);
                bM = dot4((int)wxb[8 + k], xv[k],     bM);
                bM = dot4((int)wxb[k],     xv[8 + k], bM);
            }
            const float Sx = __int_as_float(sxi);
            xA = ((float)aA + (float)aM * (1.f/127.f)) * (S2A * Sx) + biasA;
            xB = ((float)bA + (float)bM * (1.f/127.f)) * (S2B * Sx) + biasB;
        }

        // ---- recurrent dots: rowA (w[0..63]), rowB (w[64..127]), 8 scale grps
        float gaccA = 0.f;
        GRP(gaccA,  0, h0, 0, __int_as_float(scv[0]));
        GRP(gaccA,  8, h0, 8, __int_as_float(scv[1]));
        GRP(gaccA, 16, h1, 0, __int_as_float(scv[2]));
        GRP(gaccA, 24, h1, 8, __int_as_float(scv[3]));
        GRP(gaccA, 32, h2, 0, __int_as_float(scv[4]));
        GRP(gaccA, 40, h2, 8, __int_as_float(scv[5]));
        GRP(gaccA, 48, h3, 0, __int_as_float(scv[6]));
        GRP(gaccA, 56, h3, 8, __int_as_float(scv[7]));
        float gaccB = 0.f;
        GRP(gaccB,  64, h0, 0, __int_as_float(scv[0]));
        GRP(gaccB,  72, h0, 8, __int_as_float(scv[1]));
        GRP(gaccB,  80, h1, 0, __int_as_float(scv[2]));
        GRP(gaccB,  88, h1, 8, __int_as_float(scv[3]));
        GRP(gaccB,  96, h2, 0, __int_as_float(scv[4]));
        GRP(gaccB, 104, h2, 8, __int_as_float(scv[5]));
        GRP(gaccB, 112, h3, 0, __int_as_float(scv[6]));
        GRP(gaccB, 120, h3, 8, __int_as_float(scv[7]));

        const float gateA = gaccA * S1A + xA;   // i (lanes<32) / f (lanes>=32)
        const float gateB = gaccB * S1B + xB;   // g (lanes<32) / o (lanes>=32)

        // intra-wave gate exchange: lanes<32 receive f,o from lanes>=32
        const float gF = __shfl_xor(gateA, 32, 64);
        const float gO = __shfl_xor(gateB, 32, 64);

        const uint32_t wslot = (uint32_t)((t + 1) * 1993) & 2047u;
        char* hw = hb + (size_t)wslot * HREC_STRIDE;

        if (l < 32) {
            const float i_ = 1.f / (1.f + __expf(-gateA));
            const float g_ = 2.f / (1.f + __expf(-2.f * gateB)) - 1.f;
            const float f_ = 1.f / (1.f + __expf(-gF));
            const float o_ = 1.f / (1.f + __expf(-gO));
            c_state = f_ * c_state + i_ * g_;
            const float tc = 2.f / (1.f + __expf(-2.f * c_state)) - 1.f;
            const float hval = o_ * tc;
            hsb[(size_t)t * H_ + j] = (_Float16)hval;

            float m = fabsf(hval);
            #pragma unroll
            for (int s = 1; s < 32; s <<= 1) m = fmaxf(m, __shfl_xor(m, s, 64));
            m = fmaxf(m, 1e-12f);
            const int q = clamp127((int)rintf(hval * (127.f / m)));
            hw[j] = (char)(int8_t)q;
            if ((l & 31) == 0) ((float*)(hw + 256))[w_] = m * (1.f / 127.f);
        }
        xg_cur = xg_nxt;
        __syncthreads();   // h(t+1) + scales drained & visible; next s_load safe
    }
}

// -------- post: fc GEMM  out[row][o] = sum_k h[row][k]*fcw[o][k] + fcb[o] ---
__global__ __launch_bounds__(256) void fc_kernel(
    const uint32_t* __restrict__ hstore_u,   // f16 pairs, row stride 128 dwords
    const float* __restrict__ fcw, const float* __restrict__ fcb,
    float* __restrict__ out)
{
    __shared__ uint32_t hlds[64 * 128];      // 32 KB: 64 rows of h
    __shared__ uint32_t wlds[32 * 32 * 4];   // 16 KB: [chunk][o][e] f16 pairs
    const int rb = blockIdx.x * 64;
    const uint4* src = (const uint4*)(hstore_u + (size_t)rb * 128);
    for (int i = threadIdx.x; i < 2048; i += 256) ((uint4*)hlds)[i] = src[i];
    for (int i = threadIdx.x; i < 4096; i += 256) {
        const int o = i >> 7, kp = i & 127;
        union { h2_t h; uint32_t u; } cv;
        cv.h[0] = (_Float16)fcw[o * 256 + 2 * kp];
        cv.h[1] = (_Float16)fcw[o * 256 + 2 * kp + 1];
        wlds[((kp >> 2) * 32 + o) * 4 + (kp & 3)] = cv.u;
    }
    __syncthreads();

    const int o = threadIdx.x & 31, rg = threadIdx.x >> 5;
    const float bv = fcb[o];
    float acc[8];
    #pragma unroll
    for (int rr = 0; rr < 8; rr++) acc[rr] = bv;

    for (int ch = 0; ch < 32; ch++) {
        const uint4 wv = *(const uint4*)(wlds + (ch * 32 + o) * 4);
        union { uint32_t u; h2_t h; } w0, w1, w2, w3;
        w0.u = wv.x; w1.u = wv.y; w2.u = wv.z; w3.u = wv.w;
        #pragma unroll
        for (int rr = 0; rr < 8; rr++) {
            const int row = rg * 8 + rr;
            const uint4 hv = *(const uint4*)(hlds + row * 128 + ch * 4);
            union { uint32_t u; h2_t h; } x0, x1, x2, x3;
            x0.u = hv.x; x1.u = hv.y; x2.u = hv.z; x3.u = hv.w;
            float a = acc[rr];
            a = fdot2h(w0.h, x0.h, a);
            a = fdot2h(w1.h, x1.h, a);
            a = fdot2h(w2.h, x2.h, a);
            a = fdot2h(w3.h, x3.h, a);
            acc[rr] = a;
        }
    }
    #pragma unroll
    for (int rr = 0; rr < 8; rr++)
        out[(size_t)(rb + rg * 8 + rr) * O_ + o] = acc[rr];
}

extern "C" void kernel_launch(void* const* d_in, const int* in_sizes, int n_in,
                              void* d_out, int out_size, void* d_ws, size_t ws_size,
                              hipStream_t stream) {
    const float* x    = (const float*)d_in[0];
    const float* Wih  = (const float*)d_in[1];
    const float* Whh  = (const float*)d_in[2];
    const float* bih  = (const float*)d_in[3];
    const float* bhh  = (const float*)d_in[4];
    const float* fcw  = (const float*)d_in[5];
    const float* fcb  = (const float*)d_in[6];
    float* out = (float*)d_out;

    char* ws = (char*)d_ws;
    uint32_t* qwhh = (uint32_t*)(ws + QWHH_OFF);
    uint32_t* qwih = (uint32_t*)(ws + QWIH_OFF);
    float*    s1   = (float*)(ws + S1_OFF);
    float*    s2   = (float*)(ws + S2_OFF);
    float*    bias = (float*)(ws + BIAS_OFF);
    char*     hbuf = ws + HBUF_OFF;
    _Float16* hstore = (_Float16*)(ws + HSTORE_OFF);
    uint32_t* xqp  = (uint32_t*)(ws + XQ_OFF);
    float*    xsp  = (float*)(ws + XS_OFF);
    uint32_t* xgp  = (uint32_t*)(ws + XG_OFF);

    const bool use_xg = (ws_size >= FULL_NEED);

    prep_w<<<G4, 64, 0, stream>>>(Whh, Wih, bih, bhh, qwhh, qwih, s1, s2, bias);
    if (use_xg) {
        gemm_xg<<<512, 512, 0, stream>>>(x, Wih, bias, xgp);
        lstm_main<true><<<B_, 512, 0, stream>>>(qwhh, qwih, s1, s2, bias,
                                                xgp, nullptr, nullptr, hbuf, hstore);
    } else {
        prep_x<<<(B_ * T_) / 64, 256, 0, stream>>>(x, xqp, xsp);
        lstm_main<false><<<B_, 512, 0, stream>>>(qwhh, qwih, s1, s2, bias,
                                                 nullptr, xqp, xsp, hbuf, hstore);
    }
    fc_kernel<<<(B_ * T_) / 64, 256, 0, stream>>>((const uint32_t*)hstore, fcw, fcb, out);
}

// Round 4
// 4080.807 us; speedup vs baseline: 1.1045x; 1.1045x over previous
//
#include <hip/hip_runtime.h>
#include <cstdint>

// LSTM fused kernel for MI355X — round 4.
// 64 blocks (1/batch) x 512 threads (2 gate-rows/thread), full T-loop in-kernel.
// vs r3: (1) amdgpu_waves_per_eu(2,2) forces exactly-2-waves/EU so the 144-dword
// weight arrays get the full 256-VGPR arch budget (r2/r3 put them in AGPRs ->
// accvgpr_read per dot4, ~2.5x VALU); (2) x-path folded into the step as int8
// hi/lo dots from a 72-B record s_loaded together with the h-record (no 268-MB
// xg buffer, no fallback); (3) identity h-slots with f16 h in the record tail
// (stride 800) so the fc post-pass reads exact f16 h; ws total 114.7 MB.

#define B_  64
#define T_  2048
#define I_  32
#define H_  256
#define G4  1024
#define O_  32

typedef int v16i __attribute__((ext_vector_type(16)));
typedef int v8i  __attribute__((ext_vector_type(8)));
typedef _Float16 h2_t __attribute__((ext_vector_type(2)));

#if __has_builtin(__builtin_amdgcn_sdot4)
__device__ __forceinline__ int dot4(int a, int b, int c) {
    return __builtin_amdgcn_sdot4(a, b, c, false);
}
#else
__device__ __forceinline__ int dot4(int a, int b, int c) {
    c += (int)(int8_t)(a)        * (int)(int8_t)(b);
    c += (int)(int8_t)(a >> 8)   * (int)(int8_t)(b >> 8);
    c += (int)(int8_t)(a >> 16)  * (int)(int8_t)(b >> 16);
    c += (int)(int8_t)(a >> 24)  * (int)(int8_t)(b >> 24);
    return c;
}
#endif

__device__ __forceinline__ float fdot2h(h2_t a, h2_t b, float c) {
#if __has_builtin(__builtin_amdgcn_fdot2)
    return __builtin_amdgcn_fdot2(a, b, c, false);
#else
    return c + (float)a[0] * (float)b[0] + (float)a[1] * (float)b[1];
#endif
}

// ---------------- ws layout ----------------
// qwhh : uint32 [128][512]  @0        (262144 B)
// qwih : uint32 [16][512]   @262144   (32768 B)   W_ih int8 (single, per-row scale)
// s1   : float [1024]       @294912
// s2   : float [1024]       @299008
// bias : float [1024]       @303104
// xq   : [B*T] records of 72 B @307200   (9437184 B)  [8dw hi][8dw lo][scale]
// hbuf : [B] x 2049 records of 800 B @9744384 (104908800 B)
//        record: [256 int8 h][8 f32 group scales][512 B f16 h]
// total 114,653,184 B (< 118.3 MB proven writable in r3)
#define QWHH_OFF 0u
#define QWIH_OFF 262144u
#define S1_OFF   294912u
#define S2_OFF   299008u
#define BIAS_OFF 303104u
#define XQ_OFF   307200u
#define HBUF_OFF 9744384u
#define XREC  72
#define HREC  800
#define HSLOTS 2049

__device__ __forceinline__ uint32_t pack_q(int q0, int q1, int q2, int q3) {
    return  ((uint32_t)(uint8_t)(int8_t)q0)
          | (((uint32_t)(uint8_t)(int8_t)q1) << 8)
          | (((uint32_t)(uint8_t)(int8_t)q2) << 16)
          | (((uint32_t)(uint8_t)(int8_t)q3) << 24);
}
__device__ __forceinline__ int clamp127(int v) {
    return v < -127 ? -127 : (v > 127 ? 127 : v);
}

// column mapping shared by prep_w / lstm_main:
// thread tid: w_=tid>>6, l=tid&63, j=32*w_+(l&31)
// rowA = (l>=32) ? 256+j : j       (f or i)
// rowB = (l>=32) ? 768+j : 512+j   (o or g)

__global__ __launch_bounds__(64) void prep_w(
    const float* __restrict__ Whh, const float* __restrict__ Wih,
    const float* __restrict__ bih, const float* __restrict__ bhh,
    uint32_t* __restrict__ qwhh, uint32_t* __restrict__ qwih,
    float* __restrict__ s1, float* __restrict__ s2, float* __restrict__ bias)
{
    const int r = blockIdx.x;           // gate row 0..1023
    const int l = threadIdx.x;          // 0..63
    const int j = r & 255, g = r >> 8;
    const int col = 64 * (j >> 5) + ((g & 1) ? 32 : 0) + (j & 31);
    const int dbase = (g >= 2) ? 64 : 0;
    const int xbase = (g >= 2) ? 8 : 0;

    const float4 wv = ((const float4*)(Whh + r * H_))[l];
    float m = fmaxf(fmaxf(fabsf(wv.x), fabsf(wv.y)), fmaxf(fabsf(wv.z), fabsf(wv.w)));
    #pragma unroll
    for (int s = 1; s < 64; s <<= 1) m = fmaxf(m, __shfl_xor(m, s, 64));
    const float S1 = fmaxf(m, 1e-20f) / 127.f;

    float xm = (l < I_) ? fabsf(Wih[r * I_ + l]) : 0.f;
    #pragma unroll
    for (int s = 1; s < 64; s <<= 1) xm = fmaxf(xm, __shfl_xor(xm, s, 64));
    const float S2 = fmaxf(xm, 1e-20f) / 127.f;

    {
        const float r1 = 1.f / S1;
        qwhh[(dbase + l) * 512 + col] = pack_q(
            clamp127((int)rintf(wv.x * r1)), clamp127((int)rintf(wv.y * r1)),
            clamp127((int)rintf(wv.z * r1)), clamp127((int)rintf(wv.w * r1)));
    }
    if (l < 8) {
        const float4 xw = ((const float4*)(Wih + r * I_))[l];
        const float r2 = 1.f / S2;
        qwih[(xbase + l) * 512 + col] = pack_q(
            clamp127((int)rintf(xw.x * r2)), clamp127((int)rintf(xw.y * r2)),
            clamp127((int)rintf(xw.z * r2)), clamp127((int)rintf(xw.w * r2)));
    }
    if (l == 0) { s1[r] = S1; s2[r] = S2; bias[r] = bih[r] + bhh[r]; }
}

// -------- prep: quantize x into 72-B records (hi/lo int8 + scale) --------
__global__ __launch_bounds__(256) void prep_x(
    const float* __restrict__ x, char* __restrict__ xq)
{
    __shared__ float xb[64 * 32];
    const int base = blockIdx.x * 64 * 32;
    for (int i = threadIdx.x; i < 2048; i += 256) xb[i] = x[base + i];
    __syncthreads();
    const int t = threadIdx.x;
    if (t < 64) {
        float m = 0.f;
        for (int k = 0; k < 32; k++) m = fmaxf(m, fabsf(xb[t * 32 + k]));
        const float S = fmaxf(m, 1e-20f) / 127.f;
        const float rS = 1.f / S;
        const int row = blockIdx.x * 64 + t;
        uint32_t* rec = (uint32_t*)(xq + (size_t)row * XREC);
        for (int jj = 0; jj < 8; jj++) {
            int qa[4], qb[4];
            for (int e = 0; e < 4; e++) {
                float v = xb[t * 32 + jj * 4 + e] * rS;
                int a = clamp127((int)rintf(v));
                int b = clamp127((int)rintf((v - (float)a) * 127.f));
                qa[e] = a; qb[e] = b;
            }
            rec[jj]     = pack_q(qa[0], qa[1], qa[2], qa[3]);
            rec[8 + jj] = pack_q(qb[0], qb[1], qb[2], qb[3]);
        }
        ((float*)rec)[16] = S;
    }
}

#define GRP(GACC, WOFF, HV, HOFF, SC) { int acc_ = 0; \
    acc_ = dot4((int)w[(WOFF)+0], HV[(HOFF)+0], acc_); \
    acc_ = dot4((int)w[(WOFF)+1], HV[(HOFF)+1], acc_); \
    acc_ = dot4((int)w[(WOFF)+2], HV[(HOFF)+2], acc_); \
    acc_ = dot4((int)w[(WOFF)+3], HV[(HOFF)+3], acc_); \
    acc_ = dot4((int)w[(WOFF)+4], HV[(HOFF)+4], acc_); \
    acc_ = dot4((int)w[(WOFF)+5], HV[(HOFF)+5], acc_); \
    acc_ = dot4((int)w[(WOFF)+6], HV[(HOFF)+6], acc_); \
    acc_ = dot4((int)w[(WOFF)+7], HV[(HOFF)+7], acc_); \
    GACC = fmaf((float)acc_, (SC), GACC); }

// -------- main: full LSTM, one block per batch, 512 threads --------
__global__
__attribute__((amdgpu_flat_work_group_size(512, 512)))
__attribute__((amdgpu_waves_per_eu(2, 2)))
void lstm_main(
    const uint32_t* __restrict__ qwhh, const uint32_t* __restrict__ qwih,
    const float* __restrict__ s1v, const float* __restrict__ s2v,
    const float* __restrict__ biasv, const char* __restrict__ xq,
    char* __restrict__ hbuf)
{
    const int b   = blockIdx.x;
    const int tid = threadIdx.x;
    const int w_  = tid >> 6, l = tid & 63;
    const int j   = 32 * w_ + (l & 31);
    const bool up = (l >= 32);
    const int rowA = up ? 256 + j : j;       // f or i
    const int rowB = up ? 768 + j : 512 + j; // o or g

    uint32_t w[128];
    #pragma unroll
    for (int d = 0; d < 128; d++) w[d] = qwhh[d * 512 + tid];
    uint32_t wx[16];
    #pragma unroll
    for (int k = 0; k < 16; k++) wx[k] = qwih[k * 512 + tid];

    const float S1A = s1v[rowA], S1B = s1v[rowB];
    const float S2A = s2v[rowA], S2B = s2v[rowB];
    const float biasA = biasv[rowA], biasB = biasv[rowB];

    char* hb = hbuf + (size_t)b * ((size_t)HSLOTS * HREC);
    const char* xb = xq + (size_t)b * T_ * XREC;
    if (tid < 72) ((uint32_t*)hb)[tid] = 0u;   // slot 0: zero h + zero scales
    float c_state = 0.f;                        // valid for lanes l<32
    __syncthreads();

    for (int t = 0; t < T_; t++) {
        const char* hrec = hb + (size_t)t * HREC;
        const char* xrec = xb + (size_t)t * XREC;
        v16i h0, h1, h2, h3, xv; v8i scv; int sxi;
        asm volatile(
            "s_load_dwordx16 %0, %7, 0x0\n\t"
            "s_load_dwordx16 %1, %7, 0x40\n\t"
            "s_load_dwordx16 %2, %7, 0x80\n\t"
            "s_load_dwordx16 %3, %7, 0xc0\n\t"
            "s_load_dwordx8  %4, %7, 0x100\n\t"
            "s_load_dwordx16 %5, %8, 0x0\n\t"
            "s_load_dword    %6, %8, 0x40\n\t"
            "s_waitcnt lgkmcnt(0)"
            : "=&s"(h0), "=&s"(h1), "=&s"(h2), "=&s"(h3), "=&s"(scv),
              "=&s"(xv), "=&s"(sxi)
            : "s"(hrec), "s"(xrec)
            : "memory");

        // recurrent dots: rowA = w[0..63], rowB = w[64..127], 8 scale groups
        float gaccA = 0.f, gaccB = 0.f;
        GRP(gaccA,  0, h0, 0, __int_as_float(scv[0]));
        GRP(gaccA,  8, h0, 8, __int_as_float(scv[1]));
        GRP(gaccA, 16, h1, 0, __int_as_float(scv[2]));
        GRP(gaccA, 24, h1, 8, __int_as_float(scv[3]));
        GRP(gaccA, 32, h2, 0, __int_as_float(scv[4]));
        GRP(gaccA, 40, h2, 8, __int_as_float(scv[5]));
        GRP(gaccA, 48, h3, 0, __int_as_float(scv[6]));
        GRP(gaccA, 56, h3, 8, __int_as_float(scv[7]));
        GRP(gaccB,  64, h0, 0, __int_as_float(scv[0]));
        GRP(gaccB,  72, h0, 8, __int_as_float(scv[1]));
        GRP(gaccB,  80, h1, 0, __int_as_float(scv[2]));
        GRP(gaccB,  88, h1, 8, __int_as_float(scv[3]));
        GRP(gaccB,  96, h2, 0, __int_as_float(scv[4]));
        GRP(gaccB, 104, h2, 8, __int_as_float(scv[5]));
        GRP(gaccB, 112, h3, 0, __int_as_float(scv[6]));
        GRP(gaccB, 120, h3, 8, __int_as_float(scv[7]));

        // x contribution (int8 W_ih x int8 hi/lo x)
        int aA = 0, aL = 0, bA = 0, bL = 0;
        #pragma unroll
        for (int k = 0; k < 8; k++) {
            aA = dot4((int)wx[k],     xv[k],     aA);
            aL = dot4((int)wx[k],     xv[8 + k], aL);
            bA = dot4((int)wx[8 + k], xv[k],     bA);
            bL = dot4((int)wx[8 + k], xv[8 + k], bL);
        }
        const float Sx = __int_as_float(sxi);
        const float xA = ((float)aA + (float)aL * (1.f / 127.f)) * (S2A * Sx) + biasA;
        const float xB = ((float)bA + (float)bL * (1.f / 127.f)) * (S2B * Sx) + biasB;

        const float gateA = gaccA * S1A + xA;   // i (l<32) / f (l>=32)
        const float gateB = gaccB * S1B + xB;   // g (l<32) / o (l>=32)
        const float gF = __shfl_xor(gateA, 32, 64);
        const float gO = __shfl_xor(gateB, 32, 64);

        char* hw = hb + (size_t)(t + 1) * HREC;
        if (l < 32) {
            const float i_ = 1.f / (1.f + __expf(-gateA));
            const float g_ = 2.f / (1.f + __expf(-2.f * gateB)) - 1.f;
            const float f_ = 1.f / (1.f + __expf(-gF));
            const float o_ = 1.f / (1.f + __expf(-gO));
            c_state = f_ * c_state + i_ * g_;
            const float tc = 2.f / (1.f + __expf(-2.f * c_state)) - 1.f;
            const float hval = o_ * tc;

            // group (per-wave) max + quantize
            float m = fabsf(hval);
            #pragma unroll
            for (int s = 1; s < 32; s <<= 1) m = fmaxf(m, __shfl_xor(m, s, 64));
            m = fmaxf(m, 1e-12f);
            const int q = clamp127((int)rintf(hval * (127.f / m)));

            // pack int8 x4 -> dwords at lanes 0 mod 4, pairs at 0 mod 8
            uint32_t q8 = (uint32_t)q & 0xffu;
            uint32_t p = q8 | (((uint32_t)__shfl_xor((int)q8, 1, 64)) << 8);
            p = p | (((uint32_t)__shfl_xor((int)p, 2, 64)) << 16);
            const uint32_t p4 = (uint32_t)__shfl_xor((int)p, 4, 64);

            // pack f16 pairs -> dwords at even lanes, uint2 at 0 mod 4
            union { _Float16 f; uint16_t u; } hc; hc.f = (_Float16)hval;
            uint32_t hh = (uint32_t)hc.u;
            uint32_t hp = hh | (((uint32_t)__shfl_xor((int)hh, 1, 64)) << 16);
            const uint32_t hp2 = (uint32_t)__shfl_xor((int)hp, 2, 64);

            if ((l & 7) == 0) *(uint2*)(hw + 32 * w_ + l) = make_uint2(p, p4);
            if ((l & 3) == 0) *(uint2*)(hw + 288 + 64 * w_ + 2 * l) = make_uint2(hp, hp2);
            if (l == 0) ((float*)(hw + 256))[w_] = m * (1.f / 127.f);
        }
        __syncthreads();   // stores drained (vmcnt) + all waves ready for t+1
    }
}

// -------- post: fc GEMM from f16 h tails --------
__global__ __launch_bounds__(256) void fc_kernel(
    const char* __restrict__ hbuf, const float* __restrict__ fcw,
    const float* __restrict__ fcb, float* __restrict__ out)
{
    __shared__ uint32_t hlds[64 * 128];      // 32 KB: 64 timesteps of f16 h
    __shared__ uint32_t wlds[32 * 32 * 4];   // 16 KB: [chunk][o][e] f16 pairs
    const int b  = blockIdx.x >> 5;
    const int t0 = (blockIdx.x & 31) * 64;
    const char* hb = hbuf + (size_t)b * ((size_t)HSLOTS * HREC);

    for (int u = threadIdx.x; u < 2048; u += 256) {
        const int r = u >> 5, c = u & 31;
        ((uint4*)hlds)[u] =
            *(const uint4*)(hb + (size_t)(t0 + r + 1) * HREC + 288 + c * 16);
    }
    for (int i = threadIdx.x; i < 4096; i += 256) {
        const int o = i >> 7, kp = i & 127;
        union { h2_t h; uint32_t u; } cv;
        cv.h[0] = (_Float16)fcw[o * 256 + 2 * kp];
        cv.h[1] = (_Float16)fcw[o * 256 + 2 * kp + 1];
        wlds[((kp >> 2) * 32 + o) * 4 + (kp & 3)] = cv.u;
    }
    __syncthreads();

    const int o = threadIdx.x & 31, rg = threadIdx.x >> 5;
    const float bv = fcb[o];
    float acc[8];
    #pragma unroll
    for (int rr = 0; rr < 8; rr++) acc[rr] = bv;

    for (int ch = 0; ch < 32; ch++) {
        const uint4 wv = *(const uint4*)(wlds + (ch * 32 + o) * 4);
        union { uint32_t u; h2_t h; } w0, w1, w2, w3;
        w0.u = wv.x; w1.u = wv.y; w2.u = wv.z; w3.u = wv.w;
        #pragma unroll
        for (int rr = 0; rr < 8; rr++) {
            const int row = rg * 8 + rr;
            const uint4 hv = *(const uint4*)(hlds + row * 128 + ch * 4);
            union { uint32_t u; h2_t h; } x0, x1, x2, x3;
            x0.u = hv.x; x1.u = hv.y; x2.u = hv.z; x3.u = hv.w;
            float a = acc[rr];
            a = fdot2h(w0.h, x0.h, a);
            a = fdot2h(w1.h, x1.h, a);
            a = fdot2h(w2.h, x2.h, a);
            a = fdot2h(w3.h, x3.h, a);
            acc[rr] = a;
        }
    }
    #pragma unroll
    for (int rr = 0; rr < 8; rr++)
        out[((size_t)b * T_ + t0 + rg * 8 + rr) * O_ + o] = acc[rr];
}

extern "C" void kernel_launch(void* const* d_in, const int* in_sizes, int n_in,
                              void* d_out, int out_size, void* d_ws, size_t ws_size,
                              hipStream_t stream) {
    const float* x    = (const float*)d_in[0];
    const float* Wih  = (const float*)d_in[1];
    const float* Whh  = (const float*)d_in[2];
    const float* bih  = (const float*)d_in[3];
    const float* bhh  = (const float*)d_in[4];
    const float* fcw  = (const float*)d_in[5];
    const float* fcb  = (const float*)d_in[6];
    float* out = (float*)d_out;

    char* ws = (char*)d_ws;
    uint32_t* qwhh = (uint32_t*)(ws + QWHH_OFF);
    uint32_t* qwih = (uint32_t*)(ws + QWIH_OFF);
    float*    s1   = (float*)(ws + S1_OFF);
    float*    s2   = (float*)(ws + S2_OFF);
    float*    bias = (float*)(ws + BIAS_OFF);
    char*     xq   = ws + XQ_OFF;
    char*     hbuf = ws + HBUF_OFF;

    prep_w<<<G4, 64, 0, stream>>>(Whh, Wih, bih, bhh, qwhh, qwih, s1, s2, bias);
    prep_x<<<(B_ * T_) / 64, 256, 0, stream>>>(x, xq);
    lstm_main<<<B_, 512, 0, stream>>>(qwhh, qwih, s1, s2, bias, xq, hbuf);
    fc_kernel<<<(B_ * T_) / 64, 256, 0, stream>>>(hbuf, fcw, fcb, out);
}

// Round 6
// 3686.224 us; speedup vs baseline: 1.2227x; 1.1070x over previous
//
#include <hip/hip_runtime.h>
#include <cstdint>

// LSTM fused kernel for MI355X — round 6.
// 64 blocks (1/batch) x 1024 threads; wave w owns gate (w>>2) for units
// 64*(w&3)..+63 (row == tid, identity mapping). Replay-proven envelope:
// __launch_bounds__(1024,4) (r2 passed replay with it), NO waves_per_eu
// attr, NO "+v" pin asm, NO sub-dword stores (r5's replay-only failure
// suspects all removed). Scale groups = 64 units = one wave -> per-wave
// shfl max, lane0 stores ONE f32 dword (4 total, distinct). Gate exchange
// via 4KB LDS (stride-1, 2 barriers/step). h records 512 B line-aligned:
// [256 int8 h][4 f32 scales][pad] -> s_load 4x dwordx16 + dwordx4; fc
// post-pass dequantizes int8 h directly (f16 tail dropped).

#define B_  64
#define T_  2048
#define I_  32
#define H_  256
#define G4  1024
#define O_  32

typedef int v16i __attribute__((ext_vector_type(16)));
typedef int v4i  __attribute__((ext_vector_type(4)));
typedef _Float16 h2_t __attribute__((ext_vector_type(2)));

#if __has_builtin(__builtin_amdgcn_sdot4)
__device__ __forceinline__ int dot4(int a, int b, int c) {
    return __builtin_amdgcn_sdot4(a, b, c, false);
}
#else
__device__ __forceinline__ int dot4(int a, int b, int c) {
    c += (int)(int8_t)(a)        * (int)(int8_t)(b);
    c += (int)(int8_t)(a >> 8)   * (int)(int8_t)(b >> 8);
    c += (int)(int8_t)(a >> 16)  * (int)(int8_t)(b >> 16);
    c += (int)(int8_t)(a >> 24)  * (int)(int8_t)(b >> 24);
    return c;
}
#endif

__device__ __forceinline__ float fdot2h(h2_t a, h2_t b, float c) {
#if __has_builtin(__builtin_amdgcn_fdot2)
    return __builtin_amdgcn_fdot2(a, b, c, false);
#else
    return c + (float)a[0] * (float)b[0] + (float)a[1] * (float)b[1];
#endif
}

// ---------------- ws layout ----------------
// qwhh : uint32 [64][1024]  @0        (262144 B)   d-th dword of row r at [d][r]
// qwih : uint32 [8][1024]   @262144   (32768 B)
// s1/s2/bias : float [1024] @294912/299008/303104
// xq   : [B*T] 72-B records @307200   (9437184 B)  [8dw hi][8dw lo][f32 scale]
// hbuf : [B] x 2049 x 512 B @9744384  (67141632 B)
//        record: [256 int8 h][4 f32 group scales (16B)][pad 240B]
// total 76,886,016 B
#define QWHH_OFF 0u
#define QWIH_OFF 262144u
#define S1_OFF   294912u
#define S2_OFF   299008u
#define BIAS_OFF 303104u
#define XQ_OFF   307200u
#define HBUF_OFF 9744384u
#define XREC  72
#define HREC  512
#define HSLOTS 2049

__device__ __forceinline__ uint32_t pack_q(int q0, int q1, int q2, int q3) {
    return  ((uint32_t)(uint8_t)(int8_t)q0)
          | (((uint32_t)(uint8_t)(int8_t)q1) << 8)
          | (((uint32_t)(uint8_t)(int8_t)q2) << 16)
          | (((uint32_t)(uint8_t)(int8_t)q3) << 24);
}
__device__ __forceinline__ int clamp127(int v) {
    return v < -127 ? -127 : (v > 127 ? 127 : v);
}

// -------- prep: quantize weights (identity column mapping: col == row) -----
__global__ __launch_bounds__(64) void prep_w(
    const float* __restrict__ Whh, const float* __restrict__ Wih,
    const float* __restrict__ bih, const float* __restrict__ bhh,
    uint32_t* __restrict__ qwhh, uint32_t* __restrict__ qwih,
    float* __restrict__ s1, float* __restrict__ s2, float* __restrict__ bias)
{
    const int r = blockIdx.x;           // gate row 0..1023
    const int l = threadIdx.x;          // 0..63

    const float4 wv = ((const float4*)(Whh + r * H_))[l];
    float m = fmaxf(fmaxf(fabsf(wv.x), fabsf(wv.y)), fmaxf(fabsf(wv.z), fabsf(wv.w)));
    #pragma unroll
    for (int s = 1; s < 64; s <<= 1) m = fmaxf(m, __shfl_xor(m, s, 64));
    const float S1 = fmaxf(m, 1e-20f) / 127.f;

    float xm = (l < I_) ? fabsf(Wih[r * I_ + l]) : 0.f;
    #pragma unroll
    for (int s = 1; s < 64; s <<= 1) xm = fmaxf(xm, __shfl_xor(xm, s, 64));
    const float S2 = fmaxf(xm, 1e-20f) / 127.f;

    {
        const float r1 = 1.f / S1;
        qwhh[l * G4 + r] = pack_q(
            clamp127((int)rintf(wv.x * r1)), clamp127((int)rintf(wv.y * r1)),
            clamp127((int)rintf(wv.z * r1)), clamp127((int)rintf(wv.w * r1)));
    }
    if (l < 8) {
        const float4 xw = ((const float4*)(Wih + r * I_))[l];
        const float r2 = 1.f / S2;
        qwih[l * G4 + r] = pack_q(
            clamp127((int)rintf(xw.x * r2)), clamp127((int)rintf(xw.y * r2)),
            clamp127((int)rintf(xw.z * r2)), clamp127((int)rintf(xw.w * r2)));
    }
    if (l == 0) { s1[r] = S1; s2[r] = S2; bias[r] = bih[r] + bhh[r]; }
}

// -------- prep: quantize x into 72-B records (hi/lo int8 + f32 scale) ------
__global__ __launch_bounds__(256) void prep_x(
    const float* __restrict__ x, char* __restrict__ xq)
{
    __shared__ float xb[64 * 32];
    const int base = blockIdx.x * 64 * 32;
    for (int i = threadIdx.x; i < 2048; i += 256) xb[i] = x[base + i];
    __syncthreads();
    const int t = threadIdx.x;
    if (t < 64) {
        float m = 0.f;
        for (int k = 0; k < 32; k++) m = fmaxf(m, fabsf(xb[t * 32 + k]));
        const float S = fmaxf(m, 1e-20f) / 127.f;
        const float rS = 1.f / S;
        const int row = blockIdx.x * 64 + t;
        uint32_t* rec = (uint32_t*)(xq + (size_t)row * XREC);
        for (int jj = 0; jj < 8; jj++) {
            int qa[4], qb[4];
            for (int e = 0; e < 4; e++) {
                float v = xb[t * 32 + jj * 4 + e] * rS;
                int a = clamp127((int)rintf(v));
                int b = clamp127((int)rintf((v - (float)a) * 127.f));
                qa[e] = a; qb[e] = b;
            }
            rec[jj]     = pack_q(qa[0], qa[1], qa[2], qa[3]);
            rec[8 + jj] = pack_q(qb[0], qb[1], qb[2], qb[3]);
        }
        ((float*)rec)[16] = S;
    }
}

#define GRP16(GACC, WOFF, HV, SC) { int a_ = 0; \
    a_ = dot4((int)w[(WOFF)+0],  HV[0],  a_); \
    a_ = dot4((int)w[(WOFF)+1],  HV[1],  a_); \
    a_ = dot4((int)w[(WOFF)+2],  HV[2],  a_); \
    a_ = dot4((int)w[(WOFF)+3],  HV[3],  a_); \
    a_ = dot4((int)w[(WOFF)+4],  HV[4],  a_); \
    a_ = dot4((int)w[(WOFF)+5],  HV[5],  a_); \
    a_ = dot4((int)w[(WOFF)+6],  HV[6],  a_); \
    a_ = dot4((int)w[(WOFF)+7],  HV[7],  a_); \
    a_ = dot4((int)w[(WOFF)+8],  HV[8],  a_); \
    a_ = dot4((int)w[(WOFF)+9],  HV[9],  a_); \
    a_ = dot4((int)w[(WOFF)+10], HV[10], a_); \
    a_ = dot4((int)w[(WOFF)+11], HV[11], a_); \
    a_ = dot4((int)w[(WOFF)+12], HV[12], a_); \
    a_ = dot4((int)w[(WOFF)+13], HV[13], a_); \
    a_ = dot4((int)w[(WOFF)+14], HV[14], a_); \
    a_ = dot4((int)w[(WOFF)+15], HV[15], a_); \
    GACC = fmaf((float)a_, (SC), GACC); }

// -------- main: full LSTM, one block per batch, 1024 threads ---------------
__global__ __launch_bounds__(1024, 4) void lstm_main(
    const uint32_t* __restrict__ qwhh, const uint32_t* __restrict__ qwih,
    const float* __restrict__ s1v, const float* __restrict__ s2v,
    const float* __restrict__ biasv, const char* __restrict__ xq,
    char* __restrict__ hbuf)
{
    const int b   = blockIdx.x;
    const int tid = threadIdx.x;
    const int w_  = tid >> 6, l = tid & 63;
    const int g   = w_ >> 2;              // 0=i 1=f 2=g 3=o
    const int u   = tid & 255;            // hidden unit for this row

    __shared__ float gbuf[1024];          // activated f,g,o (regions 256..1023)

    uint32_t w[64];
    #pragma unroll
    for (int d = 0; d < 64; d++) w[d] = qwhh[d * G4 + tid];
    uint32_t wx[8];
    #pragma unroll
    for (int k = 0; k < 8; k++) wx[k] = qwih[k * G4 + tid];

    const float S1 = s1v[tid], S2 = s2v[tid], biasr = biasv[tid];
    const float sA = (g == 2) ? 2.f : 1.f;   // g-gate: tanh = 2*sig(2x)-1
    const float mA = (g == 2) ? 2.f : 1.f;
    const float cA = (g == 2) ? -1.f : 0.f;

    char* hb = hbuf + (size_t)b * ((size_t)HSLOTS * HREC);
    const char* xb = xq + (size_t)b * T_ * XREC;
    if (tid < 68) ((uint32_t*)hb)[tid] = 0u;  // slot 0: zero h + zero scales
    float c_state = 0.f;                      // valid for waves 0-3 (g==0)
    __syncthreads();

    for (int t = 0; t < T_; t++) {
        const char* hrec = hb + (size_t)t * HREC;
        const char* xrec = xb + (size_t)t * XREC;
        v16i h0, h1, h2, h3, xv; v4i scv; int sxi;
        asm volatile(
            "s_load_dwordx16 %0, %7, 0x0\n\t"
            "s_load_dwordx16 %1, %7, 0x40\n\t"
            "s_load_dwordx16 %2, %7, 0x80\n\t"
            "s_load_dwordx16 %3, %7, 0xc0\n\t"
            "s_load_dwordx4  %4, %7, 0x100\n\t"
            "s_load_dwordx16 %5, %8, 0x0\n\t"
            "s_load_dword    %6, %8, 0x40\n\t"
            "s_waitcnt lgkmcnt(0)"
            : "=&s"(h0), "=&s"(h1), "=&s"(h2), "=&s"(h3), "=&s"(scv),
              "=&s"(xv), "=&s"(sxi)
            : "s"(hrec), "s"(xrec)
            : "memory");

        // recurrent dot: 4 scale groups of 64 units
        float gacc = 0.f;
        GRP16(gacc,  0, h0, __int_as_float(scv[0]));
        GRP16(gacc, 16, h1, __int_as_float(scv[1]));
        GRP16(gacc, 32, h2, __int_as_float(scv[2]));
        GRP16(gacc, 48, h3, __int_as_float(scv[3]));

        // x contribution (int8 W_ih x int8 hi/lo x)
        int aA = 0, aL = 0;
        #pragma unroll
        for (int k = 0; k < 8; k++) {
            aA = dot4((int)wx[k], xv[k],     aA);
            aL = dot4((int)wx[k], xv[8 + k], aL);
        }
        const float Sx = __int_as_float(sxi);
        const float xc = ((float)aA + (float)aL * (1.f / 127.f)) * (S2 * Sx) + biasr;

        const float gate = gacc * S1 + xc;
        const float y = fmaf(1.f / (1.f + __expf(-sA * gate)), mA, cA);

        if (g > 0) gbuf[(g << 8) | u] = y;   // publish activated f,g,o
        __syncthreads();                     // barrier 1: gates ready

        char* hw = hb + (size_t)(t + 1) * HREC;
        if (g == 0) {                        // waves 0-3: unit u == tid
            const float yf = gbuf[256 + tid];
            const float yg = gbuf[512 + tid];
            const float yo = gbuf[768 + tid];
            c_state = yf * c_state + y * yg;                 // f*c + i*g
            const float tc = 2.f / (1.f + __expf(-2.f * c_state)) - 1.f;
            const float hval = yo * tc;

            // per-64-unit (per-wave) max + int8 quantize
            float m = fabsf(hval);
            #pragma unroll
            for (int s = 1; s < 64; s <<= 1) m = fmaxf(m, __shfl_xor(m, s, 64));
            m = fmaxf(m, 1e-12f);
            const int q = clamp127((int)rintf(hval * (127.f / m)));

            // pack int8 x4 -> full-dword stores at lanes 0 mod 4
            uint32_t q8 = (uint32_t)q & 0xffu;
            uint32_t p = q8 | (((uint32_t)__shfl_xor((int)q8, 1, 64)) << 8);
            p = p | (((uint32_t)__shfl_xor((int)p, 2, 64)) << 16);
            if ((l & 3) == 0) *(uint32_t*)(hw + tid) = p;    // byte offset = unit
            if (l == 0) ((float*)(hw + 256))[w_] = m * (1.f / 127.f);
        }
        __syncthreads();   // barrier 2: stores drained; next s_load safe
    }
}

// -------- post: fc GEMM, dequantizing int8 h records -----------------------
__global__ __launch_bounds__(256) void fc_kernel(
    const char* __restrict__ hbuf, const float* __restrict__ fcw,
    const float* __restrict__ fcb, float* __restrict__ out)
{
    __shared__ uint32_t hlds[64 * 128];      // 32 KB: 64 timesteps of f16-pair h
    __shared__ uint32_t wlds[32 * 32 * 4];   // 16 KB: [chunk][o][e] f16 pairs
    const int b  = blockIdx.x >> 5;
    const int t0 = (blockIdx.x & 31) * 64;
    const char* hb = hbuf + (size_t)b * ((size_t)HSLOTS * HREC);

    // dequant: thread -> (record, 64-unit group)
    {
        const int rec = threadIdx.x >> 2, g4 = threadIdx.x & 3;
        const char* rp = hb + (size_t)(t0 + rec + 1) * HREC;
        const float sc = *(const float*)(rp + 256 + 4 * g4);
        #pragma unroll
        for (int qq = 0; qq < 4; qq++) {
            const uint4 d = *(const uint4*)(rp + 64 * g4 + 16 * qq);
            uint32_t vals[4] = {d.x, d.y, d.z, d.w};
            #pragma unroll
            for (int e = 0; e < 4; e++) {
                const uint32_t v = vals[e];
                union { h2_t h; uint32_t u; } p0, p1;
                p0.h[0] = (_Float16)((float)(int)(int8_t)(v)       * sc);
                p0.h[1] = (_Float16)((float)(int)(int8_t)(v >> 8)  * sc);
                p1.h[0] = (_Float16)((float)(int)(int8_t)(v >> 16) * sc);
                p1.h[1] = (_Float16)((float)(int)(int8_t)(v >> 24) * sc);
                const int di = rec * 128 + g4 * 32 + qq * 8 + e * 2;
                hlds[di]     = p0.u;
                hlds[di + 1] = p1.u;
            }
        }
    }
    for (int i = threadIdx.x; i < 4096; i += 256) {
        const int o = i >> 7, kp = i & 127;
        union { h2_t h; uint32_t u; } cv;
        cv.h[0] = (_Float16)fcw[o * 256 + 2 * kp];
        cv.h[1] = (_Float16)fcw[o * 256 + 2 * kp + 1];
        wlds[((kp >> 2) * 32 + o) * 4 + (kp & 3)] = cv.u;
    }
    __syncthreads();

    const int o = threadIdx.x & 31, rg = threadIdx.x >> 5;
    const float bv = fcb[o];
    float acc[8];
    #pragma unroll
    for (int rr = 0; rr < 8; rr++) acc[rr] = bv;

    for (int ch = 0; ch < 32; ch++) {
        const uint4 wv = *(const uint4*)(wlds + (ch * 32 + o) * 4);
        union { uint32_t u; h2_t h; } w0, w1, w2, w3;
        w0.u = wv.x; w1.u = wv.y; w2.u = wv.z; w3.u = wv.w;
        #pragma unroll
        for (int rr = 0; rr < 8; rr++) {
            const int rowi = rg * 8 + rr;
            const uint4 hv = *(const uint4*)(hlds + rowi * 128 + ch * 4);
            union { uint32_t u; h2_t h; } x0, x1, x2, x3;
            x0.u = hv.x; x1.u = hv.y; x2.u = hv.z; x3.u = hv.w;
            float a = acc[rr];
            a = fdot2h(w0.h, x0.h, a);
            a = fdot2h(w1.h, x1.h, a);
            a = fdot2h(w2.h, x2.h, a);
            a = fdot2h(w3.h, x3.h, a);
            acc[rr] = a;
        }
    }
    #pragma unroll
    for (int rr = 0; rr < 8; rr++)
        out[((size_t)b * T_ + t0 + rg * 8 + rr) * O_ + o] = acc[rr];
}

extern "C" void kernel_launch(void* const* d_in, const int* in_sizes, int n_in,
                              void* d_out, int out_size, void* d_ws, size_t ws_size,
                              hipStream_t stream) {
    const float* x    = (const float*)d_in[0];
    const float* Wih  = (const float*)d_in[1];
    const float* Whh  = (const float*)d_in[2];
    const float* bih  = (const float*)d_in[3];
    const float* bhh  = (const float*)d_in[4];
    const float* fcw  = (const float*)d_in[5];
    const float* fcb  = (const float*)d_in[6];
    float* out = (float*)d_out;

    char* ws = (char*)d_ws;
    uint32_t* qwhh = (uint32_t*)(ws + QWHH_OFF);
    uint32_t* qwih = (uint32_t*)(ws + QWIH_OFF);
    float*    s1   = (float*)(ws + S1_OFF);
    float*    s2   = (float*)(ws + S2_OFF);
    float*    bias = (float*)(ws + BIAS_OFF);
    char*     xq   = ws + XQ_OFF;
    char*     hbuf = ws + HBUF_OFF;

    prep_w<<<G4, 64, 0, stream>>>(Whh, Wih, bih, bhh, qwhh, qwih, s1, s2, bias);
    prep_x<<<(B_ * T_) / 64, 256, 0, stream>>>(x, xq);
    lstm_main<<<B_, 1024, 0, stream>>>(qwhh, qwih, s1, s2, bias, xq, hbuf);
    fc_kernel<<<(B_ * T_) / 64, 256, 0, stream>>>(hbuf, fcw, fcb, out);
}